// Round 1
// baseline (3609.144 us; speedup 1.0000x reference)
//
#include <hip/hip_runtime.h>

// JIIF fused pipeline, bf16 MFMA GEMMs.
// Shapes (fixed by problem): B=2, Cf=128, h=w=64, H=W=256, N=65536.
// Rows: r = 4*pixel + k, k in {(-1,-1),(-1,+1),(+1,-1),(+1,+1)} (vx,vy) order.

typedef unsigned short u16;
typedef unsigned int   u32;
typedef __bf16  bf16x8 __attribute__((ext_vector_type(8)));
typedef float   f32x4  __attribute__((ext_vector_type(4)));
typedef unsigned short u16x8 __attribute__((ext_vector_type(8)));

__device__ __forceinline__ u16 f2bf(float f) {
  u32 u = __float_as_uint(f);
  u32 r = (u + 0x7FFFu + ((u >> 16) & 1u)) >> 16;   // RNE
  return (u16)r;
}
__device__ __forceinline__ float bf2f(u16 v) {
  return __uint_as_float(((u32)v) << 16);
}
__device__ __forceinline__ void gload_lds16(const void* g, void* l) {
  __builtin_amdgcn_global_load_lds(
      (const __attribute__((address_space(1))) void*)g,
      (__attribute__((address_space(3))) void*)l, 16, 0, 0);
}

// ---------------------------------------------------------------------------
// Gather/assemble X rows: X[r, 0:128]=q_feat, [128:256]=q_guide_hr, [256:384]=-q_guide_lr
// One block = 64 pixels of one image row (same b, same i). Also writes rel[r,2] fp32.
// ---------------------------------------------------------------------------
__global__ __launch_bounds__(256)
void gather_x(const float* __restrict__ feat, const float* __restrict__ coord,
              const float* __restrict__ hr, const float* __restrict__ lr,
              u16* __restrict__ X, float* __restrict__ rel, int gp0)
{
  __shared__ u16 hrT[64 * 130];      // [pix][c], pad 130 to dodge bank conflicts
  __shared__ u16 fw[128 * 36];       // [c][iyi][wx]  feat window
  __shared__ u16 lw[128 * 36];       // [c][iyi][wx]  lr_guide window
  __shared__ int nhrS[64];
  __shared__ signed char wxvS[256];  // [pix][k]: window x or -1 (invalid)

  const int tid = threadIdx.x;
  const int pb  = blockIdx.x << 6;        // chunk-local pixel base
  const int gp  = gp0 + pb;               // global pixel base
  const int b   = gp >> 16;
  const int n0  = gp & 65535;
  const int i   = n0 >> 8, j0 = n0 & 255;
  const int iybase = (2 * i  - 3) >> 3;   // floor((2i-3)/8), arith shift = floor
  const int ixbase = (2 * j0 - 3) >> 3;
  const float rh = 0.015625f;             // 1/64

  if (tid < 64) {
    const int n = n0 + tid;
    const float cy = coord[(size_t)(b * 65536 + n) * 2 + 0];
    const float cx = coord[(size_t)(b * 65536 + n) * 2 + 1];
    // hr nearest (H=W=256): identity on this grid, but computed properly
    float fyh = (cy + 1.0f) * 128.0f - 0.5f;
    float fxh = (cx + 1.0f) * 128.0f - 0.5f;
    int iyh = (int)floorf(fyh + 0.5f);
    int ixh = (int)floorf(fxh + 0.5f);
    bool vh = (iyh >= 0 && iyh < 256 && ixh >= 0 && ixh < 256);
    nhrS[tid] = vh ? ((iyh << 8) + ixh) : -1;
#pragma unroll
    for (int k = 0; k < 4; ++k) {
      const float vx = (k < 2) ? -1.0f : 1.0f;
      const float vy = (k & 1) ? 1.0f : -1.0f;
      const float cyk = cy + vx * rh;
      const float cxk = cx + vy * rh;
      float fy = (cyk + 1.0f) * 32.0f - 0.5f;
      float fx = (cxk + 1.0f) * 32.0f - 0.5f;
      int iy = (int)floorf(fy + 0.5f);
      int ix = (int)floorf(fx + 0.5f);
      bool valid = (iy >= 0 && iy < 64 && ix >= 0 && ix < 64);
      int iyc = min(max(iy, 0), 63);
      int ixc = min(max(ix, 0), 63);
      float qy = valid ? ((-1.0f + rh) + (2.0f * rh) * (float)iyc) : 0.0f;
      float qx = valid ? ((-1.0f + rh) + (2.0f * rh) * (float)ixc) : 0.0f;
      const int r = ((pb + tid) << 2) + k;
      rel[2 * r + 0] = (cy - qy) * 64.0f;
      rel[2 * r + 1] = (cx - qx) * 64.0f;
      wxvS[(tid << 2) + k] = valid ? (signed char)(ix - ixbase) : (signed char)(-1);
    }
  }
  __syncthreads();

  // hr gather: coalesced over pixels (consecutive n)
  const size_t hb = (size_t)b * 128 * 65536;
  for (int e = tid; e < 64 * 128; e += 256) {
    const int pix = e & 63, c = e >> 6;
    const int n = nhrS[pix];
    const float v = (n >= 0) ? hr[hb + (size_t)c * 65536 + n] : 0.0f;
    hrT[pix * 130 + c] = f2bf(v);
  }
  // feat/lr 2x18 windows per channel
  const int iyc0 = min(max(iybase, 0), 63);
  const int iyc1 = min(max(iybase + 1, 0), 63);
  const size_t fb = (size_t)b * 128 * 4096;
  for (int e = tid; e < 128 * 2 * 18; e += 256) {
    const int wx = e % 18;
    const int t2 = e / 18;
    const int iyi = t2 & 1;
    const int c = t2 >> 1;
    const int ixw = min(max(ixbase + wx, 0), 63);
    const int iyw = iyi ? iyc1 : iyc0;
    const size_t idx = fb + (size_t)c * 4096 + iyw * 64 + ixw;
    const int lidx = c * 36 + iyi * 18 + wx;
    fw[lidx] = f2bf(feat[idx]);
    lw[lidx] = f2bf(lr[idx]);
  }
  __syncthreads();

  // write X rows (256 rows x 384 cols), coalesced over c
  for (int it = 0; it < 128; ++it) {
    const int rloc = (it << 1) + (tid >> 7);
    const int c = tid & 127;
    const int pix = rloc >> 2, k = rloc & 3;
    const int wx = wxvS[(pix << 2) + k];
    const int iyi = k >> 1;  // vx selects iy row
    u16 fv = 0, lv = 0;
    if (wx >= 0) {
      const int lidx = c * 36 + iyi * 18 + wx;
      fv = fw[lidx];
      lv = (u16)(lw[lidx] ^ 0x8000u);  // negated lr
    }
    const size_t off = (size_t)((pb << 2) + rloc) * 384;
    X[off + c]       = fv;
    X[off + 128 + c] = hrT[pix * 130 + c];
    X[off + 256 + c] = lv;
  }
}

// ---------------------------------------------------------------------------
// bf16 GEMM: C(bf16) = relu(A[M,K] @ BT[N,K]^T + bias [+ rel-term]) ; m97 recipe
// 128x128 tile, BK=32, 4 waves (2x2), 4x4 16x16x32 MFMA frags per wave.
// ---------------------------------------------------------------------------
__global__ __launch_bounds__(256)
void gemm_bias_relu(const u16* __restrict__ A, const u16* __restrict__ BT,
                    u16* __restrict__ C, const float* __restrict__ bias,
                    const float* __restrict__ rel, const float* __restrict__ w1rel,
                    int M, int N, int K)
{
  __shared__ __align__(16) u16 As[128 * 32];
  __shared__ __align__(16) u16 Bs[128 * 32];
  const int tid = threadIdx.x;
  const int w = tid >> 6;
  const int lane = tid & 63;
  const int ntiles = N >> 7;
  const int bm = blockIdx.x / ntiles;
  const int bn = blockIdx.x - bm * ntiles;
  const int m0 = bm << 7, n0 = bn << 7;

  const int lrow = tid >> 2;          // 0..63 (+ q*64)
  const int lcol = (tid & 3) << 3;    // k offset 0,8,16,24

  f32x4 acc[4][4];
#pragma unroll
  for (int ii = 0; ii < 4; ++ii)
#pragma unroll
    for (int jj = 0; jj < 4; ++jj)
      acc[ii][jj] = f32x4{0.f, 0.f, 0.f, 0.f};

  const int mbase = (w & 1) << 6;
  const int nbase = (w >> 1) << 6;
  const int fr = lane & 15;
  const int fq = lane >> 4;

  for (int kt = 0; kt < K; kt += 32) {
#pragma unroll
    for (int q = 0; q < 2; ++q) {
      const int mrow = (q << 6) + lrow;
      gload_lds16(A  + (size_t)(m0 + mrow) * K + (kt + lcol),
                  (char*)As + (q << 12) + (w << 10));
      gload_lds16(BT + (size_t)(n0 + mrow) * K + (kt + lcol),
                  (char*)Bs + (q << 12) + (w << 10));
    }
    __syncthreads();
    bf16x8 af[4], bfv[4];
#pragma unroll
    for (int ii = 0; ii < 4; ++ii) {
      af[ii]  = *(const bf16x8*)(As + ((mbase + (ii << 4) + fr) << 5) + (fq << 3));
      bfv[ii] = *(const bf16x8*)(Bs + ((nbase + (ii << 4) + fr) << 5) + (fq << 3));
    }
#pragma unroll
    for (int ii = 0; ii < 4; ++ii)
#pragma unroll
      for (int jj = 0; jj < 4; ++jj)
        acc[ii][jj] = __builtin_amdgcn_mfma_f32_16x16x32_bf16(af[ii], bfv[jj], acc[ii][jj], 0, 0, 0);
    __syncthreads();
  }

  const bool has_rel = (rel != nullptr);
#pragma unroll
  for (int ii = 0; ii < 4; ++ii) {
#pragma unroll
    for (int jj = 0; jj < 4; ++jj) {
      const int ncol = n0 + nbase + (jj << 4) + fr;
      const float bi = bias[ncol];
      float wr0 = 0.f, wr1 = 0.f;
      if (has_rel) { wr0 = w1rel[ncol]; wr1 = w1rel[1024 + ncol]; }
#pragma unroll
      for (int r = 0; r < 4; ++r) {
        const int mrow = m0 + mbase + (ii << 4) + (fq << 2) + r;
        float v = acc[ii][jj][r] + bi;
        if (has_rel) v += rel[2 * mrow] * wr0 + rel[2 * mrow + 1] * wr1;
        v = fmaxf(v, 0.f);
        C[(size_t)mrow * N + ncol] = f2bf(v);
      }
    }
  }
}

// ---------------------------------------------------------------------------
// Final: layer-5 (128->2) dot + softmax blend over the 4 branches. Wave/pixel.
// ---------------------------------------------------------------------------
__global__ __launch_bounds__(256)
void final_blend(const u16* __restrict__ A4, const float* __restrict__ w5,
                 const float* __restrict__ b5, float* __restrict__ out, int gp0)
{
  const int lane = threadIdx.x & 63;
  const int wv = threadIdx.x >> 6;
  const int p = (blockIdx.x << 2) + wv;                 // chunk-local pixel
  const u16x8 v = *(const u16x8*)(A4 + (size_t)p * 512 + lane * 8);
  const int cbase = (lane & 15) << 3;
  float s0 = 0.f, s1 = 0.f;
#pragma unroll
  for (int j = 0; j < 8; ++j) {
    const float a = bf2f(v[j]);
    s0 += a * w5[((cbase + j) << 1) + 0];
    s1 += a * w5[((cbase + j) << 1) + 1];
  }
#pragma unroll
  for (int off = 8; off >= 1; off >>= 1) {
    s0 += __shfl_xor(s0, off, 16);
    s1 += __shfl_xor(s1, off, 16);
  }
  float p0[4], p1[4];
#pragma unroll
  for (int k = 0; k < 4; ++k) {
    p0[k] = __shfl(s0, k << 4, 64) + b5[0];
    p1[k] = __shfl(s1, k << 4, 64) + b5[1];
  }
  if (lane == 0) {
    float mx = fmaxf(fmaxf(p1[0], p1[1]), fmaxf(p1[2], p1[3]));
    float e0 = expf(p1[0] - mx), e1 = expf(p1[1] - mx);
    float e2 = expf(p1[2] - mx), e3 = expf(p1[3] - mx);
    out[gp0 + p] = (p0[0] * e0 + p0[1] * e1 + p0[2] * e2 + p0[3] * e3) / (e0 + e1 + e2 + e3);
  }
}

// ---------------------------------------------------------------------------
// Weight prep: transposed bf16 weights [N,K]; W1' folds guide split:
// rows 0..127 = W1a(feat), 128..255 = W1b+W1c (q_guide_hr), 256..383 = W1c (-lr)
// ---------------------------------------------------------------------------
__global__ void prep_w1t(const float* __restrict__ w1, u16* __restrict__ w1t) {
  const int idx = blockIdx.x * 256 + threadIdx.x;
  if (idx >= 384 * 1024) return;
  const int k = idx % 384;
  const int n = idx / 384;
  float v = w1[k * 1024 + n];
  if (k >= 128 && k < 256) v += w1[(k + 128) * 1024 + n];
  w1t[idx] = f2bf(v);
}
__global__ void prep_wt(const float* __restrict__ w, u16* __restrict__ wt, int K, int N) {
  const int idx = blockIdx.x * 256 + threadIdx.x;
  if (idx >= K * N) return;
  const int k = idx % K;
  const int n = idx / K;
  wt[idx] = f2bf(w[(size_t)k * N + n]);
}

// ---------------------------------------------------------------------------
extern "C" void kernel_launch(void* const* d_in, const int* in_sizes, int n_in,
                              void* d_out, int out_size, void* d_ws, size_t ws_size,
                              hipStream_t stream)
{
  const float* feat  = (const float*)d_in[0];
  const float* coord = (const float*)d_in[1];
  const float* hrg   = (const float*)d_in[2];
  const float* lrg   = (const float*)d_in[3];
  const float* w1 = (const float*)d_in[4];
  const float* b1 = (const float*)d_in[5];
  const float* w2 = (const float*)d_in[6];
  const float* b2 = (const float*)d_in[7];
  const float* w3 = (const float*)d_in[8];
  const float* b3 = (const float*)d_in[9];
  const float* w4 = (const float*)d_in[10];
  const float* b4 = (const float*)d_in[11];
  const float* w5 = (const float*)d_in[12];
  const float* b5 = (const float*)d_in[13];
  float* out = (float*)d_out;

  char* base = (char*)d_ws;
  u16* W1T = (u16*)base;               // [1024][384]
  u16* W2T = W1T + 384 * 1024;         // [512][1024]
  u16* W3T = W2T + 1024 * 512;         // [256][512]
  u16* W4T = W3T + 512 * 256;          // [128][256]
  char* chunk_base = (char*)(W4T + 256 * 128);
  const size_t fixed = (size_t)(chunk_base - base);

  const int NP = 131072;               // B*N pixels
  // per-pixel chunk bytes: 4 rows * (X 768 + A1 2048 + A2 1024 + A3 512 + A4 256 + rel 8)
  int nc = 1;
  while (nc < 2048 && fixed + (size_t)(NP / nc) * 18464ULL > ws_size) nc <<= 1;
  const int CP = NP / nc;
  const int R = CP * 4;

  u16* X  = (u16*)chunk_base;
  u16* A1 = X  + (size_t)R * 384;
  u16* A2 = A1 + (size_t)R * 1024;
  u16* A3 = A2 + (size_t)R * 512;
  u16* A4 = A3 + (size_t)R * 256;
  float* relb = (float*)(A4 + (size_t)R * 128);

  prep_w1t<<<(384 * 1024) / 256, 256, 0, stream>>>(w1, W1T);
  prep_wt<<<(1024 * 512) / 256, 256, 0, stream>>>(w2, W2T, 1024, 512);
  prep_wt<<<(512 * 256) / 256, 256, 0, stream>>>(w3, W3T, 512, 256);
  prep_wt<<<(256 * 128) / 256, 256, 0, stream>>>(w4, W4T, 256, 128);

  for (int ch = 0; ch < nc; ++ch) {
    const int gp0 = ch * CP;
    gather_x<<<CP / 64, 256, 0, stream>>>(feat, coord, hrg, lrg, X, relb, gp0);
    gemm_bias_relu<<<(R / 128) * (1024 / 128), 256, 0, stream>>>(
        X, W1T, A1, b1, relb, w1 + 384 * 1024, R, 1024, 384);
    gemm_bias_relu<<<(R / 128) * (512 / 128), 256, 0, stream>>>(
        A1, W2T, A2, b2, nullptr, nullptr, R, 512, 1024);
    gemm_bias_relu<<<(R / 128) * (256 / 128), 256, 0, stream>>>(
        A2, W3T, A3, b3, nullptr, nullptr, R, 256, 512);
    gemm_bias_relu<<<(R / 128) * (128 / 128), 256, 0, stream>>>(
        A3, W4T, A4, b4, nullptr, nullptr, R, 128, 256);
    final_blend<<<CP / 4, 256, 0, stream>>>(A4, w5, b5, out, gp0);
  }
}

// Round 2
// 2515.394 us; speedup vs baseline: 1.4348x; 1.4348x over previous
//
#include <hip/hip_runtime.h>

// JIIF fused pipeline v2.
// Layer-1 decomposition: z1 = relu( Whr^T*hr[pixel] + Ycell[cell(pixel,k)] + rel*w1rel + b1 )
//   Whr = W1[128:256]+W1[256:384] (q_guide_hr coef), Ycell = W1[0:128]^T*feat + W1[256:384]^T*(-lr)
// Shapes fixed: B=2, Cf=128, h=w=64, H=W=256, N=65536, rows r = 4*pixel + k.

typedef unsigned short u16;
typedef unsigned int   u32;
typedef __bf16  bf16x8 __attribute__((ext_vector_type(8)));
typedef float   f32x4  __attribute__((ext_vector_type(4)));
typedef unsigned short u16x8 __attribute__((ext_vector_type(8)));

__device__ __forceinline__ u16 f2bf(float f) {
  u32 u = __float_as_uint(f);
  u32 r = (u + 0x7FFFu + ((u >> 16) & 1u)) >> 16;   // RNE
  return (u16)r;
}
__device__ __forceinline__ float bf2f(u16 v) {
  return __uint_as_float(((u32)v) << 16);
}
__device__ __forceinline__ void gload_lds16(const void* g, void* l) {
  __builtin_amdgcn_global_load_lds(
      (const __attribute__((address_space(1))) void*)g,
      (__attribute__((address_space(3))) void*)l, 16, 0, 0);
}

// ---------------------------------------------------------------------------
// gather_hr: per-pixel Xhr row (q_guide_hr, bf16[128]) + cellidx[pix][4] + rel[pix][4][2]
// One block = 64 pixels of one image row. Runs once over all 131072 pixels.
// ---------------------------------------------------------------------------
__global__ __launch_bounds__(256)
void gather_hr(const float* __restrict__ coord, const float* __restrict__ hr,
               u16* __restrict__ Xhr, int* __restrict__ cellidx, float* __restrict__ rel)
{
  __shared__ u16 hrT[64 * 130];
  __shared__ int nhrS[64];

  const int tid = threadIdx.x;
  const int pb  = blockIdx.x << 6;        // global pixel base
  const int b   = pb >> 16;
  const int n0  = pb & 65535;
  const float rh = 0.015625f;             // 1/64

  if (tid < 64) {
    const int n = n0 + tid;
    const float cy = coord[(size_t)(b * 65536 + n) * 2 + 0];
    const float cx = coord[(size_t)(b * 65536 + n) * 2 + 1];
    float fyh = (cy + 1.0f) * 128.0f - 0.5f;
    float fxh = (cx + 1.0f) * 128.0f - 0.5f;
    int iyh = (int)floorf(fyh + 0.5f);
    int ixh = (int)floorf(fxh + 0.5f);
    bool vh = (iyh >= 0 && iyh < 256 && ixh >= 0 && ixh < 256);
    nhrS[tid] = vh ? ((iyh << 8) + ixh) : -1;
#pragma unroll
    for (int k = 0; k < 4; ++k) {
      const float vx = (k < 2) ? -1.0f : 1.0f;
      const float vy = (k & 1) ? 1.0f : -1.0f;
      const float cyk = cy + vx * rh;
      const float cxk = cx + vy * rh;
      float fy = (cyk + 1.0f) * 32.0f - 0.5f;
      float fx = (cxk + 1.0f) * 32.0f - 0.5f;
      int iy = (int)floorf(fy + 0.5f);
      int ix = (int)floorf(fx + 0.5f);
      bool valid = (iy >= 0 && iy < 64 && ix >= 0 && ix < 64);
      int iyc = min(max(iy, 0), 63);
      int ixc = min(max(ix, 0), 63);
      float qy = valid ? ((-1.0f + rh) + (2.0f * rh) * (float)iyc) : 0.0f;
      float qx = valid ? ((-1.0f + rh) + (2.0f * rh) * (float)ixc) : 0.0f;
      const int p4 = ((pb + tid) << 2) + k;
      rel[2 * p4 + 0] = (cy - qy) * 64.0f;
      rel[2 * p4 + 1] = (cx - qx) * 64.0f;
      cellidx[p4] = valid ? (b * 4096 + iyc * 64 + ixc) : -1;
    }
  }
  __syncthreads();

  const size_t hb = (size_t)b * 128 * 65536;
  for (int e = tid; e < 64 * 128; e += 256) {
    const int pix = e & 63, c = e >> 6;
    const int n = nhrS[pix];
    const float v = (n >= 0) ? hr[hb + (size_t)c * 65536 + n] : 0.0f;
    hrT[pix * 130 + c] = f2bf(v);
  }
  __syncthreads();

  for (int e = tid; e < 64 * 128; e += 256) {
    const int pix = e >> 7, c = e & 127;
    Xhr[(size_t)(pb + pix) * 128 + c] = hrT[pix * 130 + c];
  }
}

// ---------------------------------------------------------------------------
// prep_cells: Xcell[cell][0:128]=feat, [128:256]=-lr  (bf16), cell = b*4096+iy*64+ix
// ---------------------------------------------------------------------------
__global__ __launch_bounds__(256)
void prep_cells(const float* __restrict__ feat, const float* __restrict__ lr,
                u16* __restrict__ Xcell)
{
  __shared__ u16 t[64 * 258];
  const int tid = threadIdx.x;
  const int cb = blockIdx.x << 6;
  const int b = cb >> 12;
  const int local = cb & 4095;
  const size_t fb = (size_t)b * 128 * 4096;
  for (int e = tid; e < 64 * 128; e += 256) {
    const int cell = e & 63, c = e >> 6;
    const size_t idx = fb + (size_t)c * 4096 + local + cell;
    t[cell * 258 + c]       = f2bf(feat[idx]);
    t[cell * 258 + 128 + c] = (u16)(f2bf(lr[idx]) ^ 0x8000u);
  }
  __syncthreads();
  for (int e = tid; e < 64 * 256; e += 256) {
    const int cell = e >> 8, c = e & 255;
    Xcell[(size_t)(cb + cell) * 256 + c] = t[cell * 258 + c];
  }
}

// ---------------------------------------------------------------------------
// Generic bf16 MFMA GEMM, m97 recipe + LDS k-chunk XOR swizzle + XCD-aware blocks.
// MODE 0: C bf16 = relu(A@B^T + bias);  MODE 1: C fp32 = A@B^T (raw).
// ---------------------------------------------------------------------------
template<int MODE>
__global__ __launch_bounds__(256)
void gemm_bt(const u16* __restrict__ A, const u16* __restrict__ BT,
             void* __restrict__ Cout, const float* __restrict__ bias,
             int M, int N, int K)
{
  __shared__ __align__(16) u16 As[128 * 32];
  __shared__ __align__(16) u16 Bs[128 * 32];
  const int tid = threadIdx.x;
  const int w = tid >> 6;
  const int lane = tid & 63;
  const int ntn = N >> 7;
  const int nmt = M >> 7;
  int bm, bn;
  if ((nmt & 7) == 0) {
    const int xcd = blockIdx.x & 7;
    const int t = blockIdx.x >> 3;
    bn = t % ntn;
    bm = xcd * (nmt >> 3) + t / ntn;
  } else {
    bm = blockIdx.x / ntn;
    bn = blockIdx.x - bm * ntn;
  }
  const int m0 = bm << 7, n0 = bn << 7;

  const int lrow = tid >> 2;                 // 0..63
  const int cc   = tid & 3;                  // physical 16B chunk
  const int sw   = cc ^ ((lrow >> 1) & 3);   // global k-chunk this lane fetches
  const int gcol = sw << 3;

  f32x4 acc[4][4];
#pragma unroll
  for (int ii = 0; ii < 4; ++ii)
#pragma unroll
    for (int jj = 0; jj < 4; ++jj)
      acc[ii][jj] = f32x4{0.f, 0.f, 0.f, 0.f};

  const int mbase = (w & 1) << 6;
  const int nbase = (w >> 1) << 6;
  const int fr = lane & 15;
  const int fq = lane >> 4;
  const int rchunk = (fq ^ ((fr >> 1) & 3)) << 3;   // un-swizzled frag chunk offset (u16 units)

  for (int kt = 0; kt < K; kt += 32) {
#pragma unroll
    for (int q = 0; q < 2; ++q) {
      const int mrow = (q << 6) + lrow;
      gload_lds16(A  + (size_t)(m0 + mrow) * K + (kt + gcol),
                  (char*)As + (q << 12) + (w << 10));
      gload_lds16(BT + (size_t)(n0 + mrow) * K + (kt + gcol),
                  (char*)Bs + (q << 12) + (w << 10));
    }
    __syncthreads();
    bf16x8 af[4], bfv[4];
#pragma unroll
    for (int ii = 0; ii < 4; ++ii) {
      af[ii]  = *(const bf16x8*)(As + ((mbase + (ii << 4) + fr) << 5) + rchunk);
      bfv[ii] = *(const bf16x8*)(Bs + ((nbase + (ii << 4) + fr) << 5) + rchunk);
    }
#pragma unroll
    for (int ii = 0; ii < 4; ++ii)
#pragma unroll
      for (int jj = 0; jj < 4; ++jj)
        acc[ii][jj] = __builtin_amdgcn_mfma_f32_16x16x32_bf16(af[ii], bfv[jj], acc[ii][jj], 0, 0, 0);
    __syncthreads();
  }

#pragma unroll
  for (int jj = 0; jj < 4; ++jj) {
    const int ncol = n0 + nbase + (jj << 4) + fr;
    const float bi = (MODE == 0) ? bias[ncol] : 0.f;
#pragma unroll
    for (int ii = 0; ii < 4; ++ii) {
#pragma unroll
      for (int r = 0; r < 4; ++r) {
        const int mrow = m0 + mbase + (ii << 4) + (fq << 2) + r;
        if (MODE == 0) {
          float v = fmaxf(acc[ii][jj][r] + bi, 0.f);
          ((u16*)Cout)[(size_t)mrow * N + ncol] = f2bf(v);
        } else {
          ((float*)Cout)[(size_t)mrow * N + ncol] = acc[ii][jj][r];
        }
      }
    }
  }
}

// ---------------------------------------------------------------------------
// gemm1f: Yhr = Xhr[CP,128] @ W1hrT[1024,128]^T ; fused epilogue expands to 4
// branch rows: A1[(pix*4+k)] = relu(Yhr + b1 + Ycell[cell] + rel*w1rel)
// ---------------------------------------------------------------------------
__global__ __launch_bounds__(256)
void gemm1f(const u16* __restrict__ Xhr, const u16* __restrict__ W1hrT,
            u16* __restrict__ A1, const float* __restrict__ b1,
            const float* __restrict__ w1, const float* __restrict__ Ycell,
            const int* __restrict__ cellidx, const float* __restrict__ rel,
            int CP, int gp0)
{
  __shared__ __align__(16) u16 As[128 * 32];
  __shared__ __align__(16) u16 Bs[128 * 32];
  const int tid = threadIdx.x;
  const int w = tid >> 6;
  const int lane = tid & 63;
  const int ntn = 8;                     // N=1024
  const int nmt = CP >> 7;
  int bm, bn;
  if ((nmt & 7) == 0) {
    const int xcd = blockIdx.x & 7;
    const int t = blockIdx.x >> 3;
    bn = t % ntn;
    bm = xcd * (nmt >> 3) + t / ntn;
  } else {
    bm = blockIdx.x / ntn;
    bn = blockIdx.x - bm * ntn;
  }
  const int m0 = bm << 7, n0 = bn << 7;

  const int lrow = tid >> 2;
  const int cc   = tid & 3;
  const int gcol = (cc ^ ((lrow >> 1) & 3)) << 3;

  f32x4 acc[4][4];
#pragma unroll
  for (int ii = 0; ii < 4; ++ii)
#pragma unroll
    for (int jj = 0; jj < 4; ++jj)
      acc[ii][jj] = f32x4{0.f, 0.f, 0.f, 0.f};

  const int mbase = (w & 1) << 6;
  const int nbase = (w >> 1) << 6;
  const int fr = lane & 15;
  const int fq = lane >> 4;
  const int rchunk = (fq ^ ((fr >> 1) & 3)) << 3;

  for (int kt = 0; kt < 128; kt += 32) {
#pragma unroll
    for (int q = 0; q < 2; ++q) {
      const int mrow = (q << 6) + lrow;
      gload_lds16(Xhr   + (size_t)(m0 + mrow) * 128 + (kt + gcol),
                  (char*)As + (q << 12) + (w << 10));
      gload_lds16(W1hrT + (size_t)(n0 + mrow) * 128 + (kt + gcol),
                  (char*)Bs + (q << 12) + (w << 10));
    }
    __syncthreads();
    bf16x8 af[4], bfv[4];
#pragma unroll
    for (int ii = 0; ii < 4; ++ii) {
      af[ii]  = *(const bf16x8*)(As + ((mbase + (ii << 4) + fr) << 5) + rchunk);
      bfv[ii] = *(const bf16x8*)(Bs + ((nbase + (ii << 4) + fr) << 5) + rchunk);
    }
#pragma unroll
    for (int ii = 0; ii < 4; ++ii)
#pragma unroll
      for (int jj = 0; jj < 4; ++jj)
        acc[ii][jj] = __builtin_amdgcn_mfma_f32_16x16x32_bf16(af[ii], bfv[jj], acc[ii][jj], 0, 0, 0);
    __syncthreads();
  }

  // epilogue: 4 branch rows per accumulator element
  float bi[4], wr0[4], wr1[4];
#pragma unroll
  for (int jj = 0; jj < 4; ++jj) {
    const int ncol = n0 + nbase + (jj << 4) + fr;
    bi[jj]  = b1[ncol];
    wr0[jj] = w1[384 * 1024 + ncol];
    wr1[jj] = w1[385 * 1024 + ncol];
  }
#pragma unroll
  for (int ii = 0; ii < 4; ++ii) {
#pragma unroll
    for (int r = 0; r < 4; ++r) {
      const int pix = m0 + mbase + (ii << 4) + (fq << 2) + r;   // chunk-local
      const int gpix = gp0 + pix;
      const int4  civ = *(const int4*)(cellidx + (size_t)gpix * 4);
      const float4 ra = *(const float4*)(rel + (size_t)gpix * 8);
      const float4 rb = *(const float4*)(rel + (size_t)gpix * 8 + 4);
      const int   cis[4]  = {civ.x, civ.y, civ.z, civ.w};
      const float ry[4]   = {ra.x, ra.z, rb.x, rb.z};
      const float rx[4]   = {ra.y, ra.w, rb.y, rb.w};
#pragma unroll
      for (int jj = 0; jj < 4; ++jj) {
        const int ncol = n0 + nbase + (jj << 4) + fr;
        const float base = acc[ii][jj][r] + bi[jj];
#pragma unroll
        for (int k = 0; k < 4; ++k) {
          const float yc = (cis[k] >= 0) ? Ycell[(size_t)cis[k] * 1024 + ncol] : 0.f;
          float v = base + yc + ry[k] * wr0[jj] + rx[k] * wr1[jj];
          v = fmaxf(v, 0.f);
          A1[(size_t)((pix << 2) + k) * 1024 + ncol] = f2bf(v);
        }
      }
    }
  }
}

// ---------------------------------------------------------------------------
// Final: layer-5 (128->2) dot + softmax blend over the 4 branches. Wave/pixel.
// ---------------------------------------------------------------------------
__global__ __launch_bounds__(256)
void final_blend(const u16* __restrict__ A4, const float* __restrict__ w5,
                 const float* __restrict__ b5, float* __restrict__ out, int gp0)
{
  const int lane = threadIdx.x & 63;
  const int wv = threadIdx.x >> 6;
  const int p = (blockIdx.x << 2) + wv;                 // chunk-local pixel
  const u16x8 v = *(const u16x8*)(A4 + (size_t)p * 512 + lane * 8);
  const int cbase = (lane & 15) << 3;
  float s0 = 0.f, s1 = 0.f;
#pragma unroll
  for (int j = 0; j < 8; ++j) {
    const float a = bf2f(v[j]);
    s0 += a * w5[((cbase + j) << 1) + 0];
    s1 += a * w5[((cbase + j) << 1) + 1];
  }
#pragma unroll
  for (int off = 8; off >= 1; off >>= 1) {
    s0 += __shfl_xor(s0, off, 16);
    s1 += __shfl_xor(s1, off, 16);
  }
  float p0[4], p1[4];
#pragma unroll
  for (int k = 0; k < 4; ++k) {
    p0[k] = __shfl(s0, k << 4, 64) + b5[0];
    p1[k] = __shfl(s1, k << 4, 64) + b5[1];
  }
  if (lane == 0) {
    float mx = fmaxf(fmaxf(p1[0], p1[1]), fmaxf(p1[2], p1[3]));
    float e0 = expf(p1[0] - mx), e1 = expf(p1[1] - mx);
    float e2 = expf(p1[2] - mx), e3 = expf(p1[3] - mx);
    out[gp0 + p] = (p0[0] * e0 + p0[1] * e1 + p0[2] * e2 + p0[3] * e3) / (e0 + e1 + e2 + e3);
  }
}

// ---------------------------------------------------------------------------
// Weight prep
// ---------------------------------------------------------------------------
__global__ void prep_w1hr(const float* __restrict__ w1, u16* __restrict__ o) {
  const int idx = blockIdx.x * 256 + threadIdx.x;       // [1024][128]
  const int n = idx >> 7, k = idx & 127;
  o[idx] = f2bf(w1[(128 + k) * 1024 + n] + w1[(256 + k) * 1024 + n]);
}
__global__ void prep_w1cell(const float* __restrict__ w1, u16* __restrict__ o) {
  const int idx = blockIdx.x * 256 + threadIdx.x;       // [1024][256]
  const int n = idx >> 8, k = idx & 255;
  const float v = (k < 128) ? w1[k * 1024 + n] : w1[(128 + k) * 1024 + n];
  o[idx] = f2bf(v);
}
__global__ void prep_wt(const float* __restrict__ w, u16* __restrict__ wt, int K, int N) {
  const int idx = blockIdx.x * 256 + threadIdx.x;
  if (idx >= K * N) return;
  const int k = idx % K;
  const int n = idx / K;
  wt[idx] = f2bf(w[(size_t)k * N + n]);
}

// ---------------------------------------------------------------------------
extern "C" void kernel_launch(void* const* d_in, const int* in_sizes, int n_in,
                              void* d_out, int out_size, void* d_ws, size_t ws_size,
                              hipStream_t stream)
{
  const float* feat  = (const float*)d_in[0];
  const float* coord = (const float*)d_in[1];
  const float* hrg   = (const float*)d_in[2];
  const float* lrg   = (const float*)d_in[3];
  const float* w1 = (const float*)d_in[4];
  const float* b1 = (const float*)d_in[5];
  const float* w2 = (const float*)d_in[6];
  const float* b2 = (const float*)d_in[7];
  const float* w3 = (const float*)d_in[8];
  const float* b3 = (const float*)d_in[9];
  const float* w4 = (const float*)d_in[10];
  const float* b4 = (const float*)d_in[11];
  const float* w5 = (const float*)d_in[12];
  const float* b5 = (const float*)d_in[13];
  float* out = (float*)d_out;

  char* base = (char*)d_ws;
  u16* W1hrT   = (u16*)base;                       // [1024][128]
  u16* W1cellT = W1hrT + 1024 * 128;               // [1024][256]
  u16* W2T     = W1cellT + 1024 * 256;             // [512][1024]
  u16* W3T     = W2T + 512 * 1024;                 // [256][512]
  u16* W4T     = W3T + 256 * 512;                  // [128][256]
  u16* Xcell   = W4T + 128 * 256;                  // [8192][256]
  float* Ycell = (float*)(Xcell + 8192 * 256);     // [8192][1024] fp32
  u16* Xhr     = (u16*)(Ycell + (size_t)8192 * 1024); // [131072][128]
  float* relb  = (float*)(Xhr + (size_t)131072 * 128); // [131072][4][2]
  int* cellidx = (int*)(relb + (size_t)131072 * 8);    // [131072][4]
  char* chunk_base = (char*)(cellidx + (size_t)131072 * 4);
  const size_t fixed = (size_t)(chunk_base - base);

  const int NP = 131072;
  // per-pixel chunk bytes: 4 rows * (A1 2048 + A2 1024 + A3 512 + A4 256) = 15360
  int nc = 1;
  while (nc < 128 && fixed + (size_t)(NP / nc) * 15360ULL > ws_size) nc <<= 1;
  const int CP = NP / nc;
  const int R = CP * 4;

  u16* A1 = (u16*)chunk_base;
  u16* A2 = A1 + (size_t)R * 1024;
  u16* A3 = A2 + (size_t)R * 512;
  u16* A4 = A3 + (size_t)R * 256;

  prep_w1hr<<<(1024 * 128) / 256, 256, 0, stream>>>(w1, W1hrT);
  prep_w1cell<<<(1024 * 256) / 256, 256, 0, stream>>>(w1, W1cellT);
  prep_wt<<<(1024 * 512) / 256, 256, 0, stream>>>(w2, W2T, 1024, 512);
  prep_wt<<<(512 * 256) / 256, 256, 0, stream>>>(w3, W3T, 512, 256);
  prep_wt<<<(256 * 128) / 256, 256, 0, stream>>>(w4, W4T, 256, 128);
  gather_hr<<<NP / 64, 256, 0, stream>>>(coord, hrg, Xhr, cellidx, relb);
  prep_cells<<<8192 / 64, 256, 0, stream>>>(feat, lrg, Xcell);
  // Ycell = Xcell @ W1cellT^T  (fp32, no bias/relu)
  gemm_bt<1><<<(8192 / 128) * (1024 / 128), 256, 0, stream>>>(
      Xcell, W1cellT, (void*)Ycell, nullptr, 8192, 1024, 256);

  for (int ch = 0; ch < nc; ++ch) {
    const int gp0 = ch * CP;
    gemm1f<<<(CP / 128) * (1024 / 128), 256, 0, stream>>>(
        Xhr + (size_t)gp0 * 128, W1hrT, A1, b1, w1, Ycell, cellidx, relb, CP, gp0);
    gemm_bt<0><<<(R / 128) * (512 / 128), 256, 0, stream>>>(
        A1, W2T, (void*)A2, b2, R, 512, 1024);
    gemm_bt<0><<<(R / 128) * (256 / 128), 256, 0, stream>>>(
        A2, W3T, (void*)A3, b3, R, 256, 512);
    gemm_bt<0><<<(R / 128) * (128 / 128), 256, 0, stream>>>(
        A3, W4T, (void*)A4, b4, R, 128, 256);
    final_blend<<<CP / 4, 256, 0, stream>>>(A4, w5, b5, out, gp0);
  }
}

// Round 3
// 1937.410 us; speedup vs baseline: 1.8629x; 1.2983x over previous
//
#include <hip/hip_runtime.h>

// JIIF fused pipeline v3.
// z1 = relu( Yhr[pixel] + Ycell[cell(pixel,k)] + rel*w1rel + b1 )
//   Yhr  = hr_guide_row @ (W1[128:256]+W1[256:384])   (per pixel, bf16 GEMM)
//   Ycell= [feat | -lr] @ W1[[0:128],[256:384]]        (per low-res cell, fp32)
// Then layers 2..4 bf16 GEMMs; layer-4 epilogue fuses layer-5 dot + softmax blend.

typedef unsigned short u16;
typedef unsigned int   u32;
typedef __bf16  bf16x8 __attribute__((ext_vector_type(8)));
typedef float   f32x4  __attribute__((ext_vector_type(4)));
typedef unsigned short u16x8 __attribute__((ext_vector_type(8)));
typedef unsigned short u16x4 __attribute__((ext_vector_type(4)));

__device__ __forceinline__ u16 f2bf(float f) {
  u32 u = __float_as_uint(f);
  u32 r = (u + 0x7FFFu + ((u >> 16) & 1u)) >> 16;   // RNE
  return (u16)r;
}
__device__ __forceinline__ float bf2f(u16 v) {
  return __uint_as_float(((u32)v) << 16);
}
__device__ __forceinline__ void gload_lds16(const void* g, void* l) {
  __builtin_amdgcn_global_load_lds(
      (const __attribute__((address_space(1))) void*)g,
      (__attribute__((address_space(3))) void*)l, 16, 0, 0);
}

// ---------------------------------------------------------------------------
// gather_hr: per-pixel Xhr row (q_guide_hr, bf16[128]) + cellidx[pix][4] + rel[pix][4][2]
// ---------------------------------------------------------------------------
__global__ __launch_bounds__(256)
void gather_hr(const float* __restrict__ coord, const float* __restrict__ hr,
               u16* __restrict__ Xhr, int* __restrict__ cellidx, float* __restrict__ rel)
{
  __shared__ u16 hrT[64 * 130];
  __shared__ int nhrS[64];

  const int tid = threadIdx.x;
  const int pb  = blockIdx.x << 6;        // global pixel base
  const int b   = pb >> 16;
  const int n0  = pb & 65535;
  const float rh = 0.015625f;             // 1/64

  if (tid < 64) {
    const int n = n0 + tid;
    const float cy = coord[(size_t)(b * 65536 + n) * 2 + 0];
    const float cx = coord[(size_t)(b * 65536 + n) * 2 + 1];
    float fyh = (cy + 1.0f) * 128.0f - 0.5f;
    float fxh = (cx + 1.0f) * 128.0f - 0.5f;
    int iyh = (int)floorf(fyh + 0.5f);
    int ixh = (int)floorf(fxh + 0.5f);
    bool vh = (iyh >= 0 && iyh < 256 && ixh >= 0 && ixh < 256);
    nhrS[tid] = vh ? ((iyh << 8) + ixh) : -1;
#pragma unroll
    for (int k = 0; k < 4; ++k) {
      const float vx = (k < 2) ? -1.0f : 1.0f;
      const float vy = (k & 1) ? 1.0f : -1.0f;
      const float cyk = cy + vx * rh;
      const float cxk = cx + vy * rh;
      float fy = (cyk + 1.0f) * 32.0f - 0.5f;
      float fx = (cxk + 1.0f) * 32.0f - 0.5f;
      int iy = (int)floorf(fy + 0.5f);
      int ix = (int)floorf(fx + 0.5f);
      bool valid = (iy >= 0 && iy < 64 && ix >= 0 && ix < 64);
      int iyc = min(max(iy, 0), 63);
      int ixc = min(max(ix, 0), 63);
      float qy = valid ? ((-1.0f + rh) + (2.0f * rh) * (float)iyc) : 0.0f;
      float qx = valid ? ((-1.0f + rh) + (2.0f * rh) * (float)ixc) : 0.0f;
      const int p4 = ((pb + tid) << 2) + k;
      rel[2 * p4 + 0] = (cy - qy) * 64.0f;
      rel[2 * p4 + 1] = (cx - qx) * 64.0f;
      cellidx[p4] = valid ? (b * 4096 + iyc * 64 + ixc) : -1;
    }
  }
  __syncthreads();

  const size_t hb = (size_t)b * 128 * 65536;
  for (int e = tid; e < 64 * 128; e += 256) {
    const int pix = e & 63, c = e >> 6;
    const int n = nhrS[pix];
    const float v = (n >= 0) ? hr[hb + (size_t)c * 65536 + n] : 0.0f;
    hrT[pix * 130 + c] = f2bf(v);
  }
  __syncthreads();

  for (int e = tid; e < 64 * 128; e += 256) {
    const int pix = e >> 7, c = e & 127;
    Xhr[(size_t)(pb + pix) * 128 + c] = hrT[pix * 130 + c];
  }
}

// ---------------------------------------------------------------------------
// prep_cells: Xcell[cell][0:128]=feat, [128:256]=-lr  (bf16)
// ---------------------------------------------------------------------------
__global__ __launch_bounds__(256)
void prep_cells(const float* __restrict__ feat, const float* __restrict__ lr,
                u16* __restrict__ Xcell)
{
  __shared__ u16 t[64 * 258];
  const int tid = threadIdx.x;
  const int cb = blockIdx.x << 6;
  const int b = cb >> 12;
  const int local = cb & 4095;
  const size_t fb = (size_t)b * 128 * 4096;
  for (int e = tid; e < 64 * 128; e += 256) {
    const int cell = e & 63, c = e >> 6;
    const size_t idx = fb + (size_t)c * 4096 + local + cell;
    t[cell * 258 + c]       = f2bf(feat[idx]);
    t[cell * 258 + 128 + c] = (u16)(f2bf(lr[idx]) ^ 0x8000u);
  }
  __syncthreads();
  for (int e = tid; e < 64 * 256; e += 256) {
    const int cell = e >> 8, c = e & 255;
    Xcell[(size_t)(cb + cell) * 256 + c] = t[cell * 258 + c];
  }
}

// ---------------------------------------------------------------------------
// Generic bf16 MFMA GEMM, m97 recipe + LDS k-chunk XOR swizzle + XCD-aware blocks.
// MODE 0: C bf16 = relu(A@B^T + bias)
// MODE 1: C fp32 = A@B^T
// MODE 2: N==128; relu(A@B^T+bias) -> LDS tile -> fused layer5 dot + softmax -> out
// MODE 3: C bf16 = A@B^T (raw)
// ---------------------------------------------------------------------------
template<int MODE>
__global__ __launch_bounds__(256)
void gemm_bt(const u16* __restrict__ A, const u16* __restrict__ BT,
             void* __restrict__ Cout, const float* __restrict__ bias,
             int M, int N, int K,
             const float* __restrict__ w5, const float* __restrict__ b5,
             float* __restrict__ outp, int gp0)
{
  __shared__ __align__(16) u16 As[128 * 32];
  __shared__ __align__(16) u16 Bs[128 * 32];
  const int tid = threadIdx.x;
  const int w = tid >> 6;
  const int lane = tid & 63;
  const int ntn = N >> 7;
  const int nmt = M >> 7;
  int bm, bn;
  if ((nmt & 7) == 0) {
    const int xcd = blockIdx.x & 7;
    const int t = blockIdx.x >> 3;
    bn = t % ntn;
    bm = xcd * (nmt >> 3) + t / ntn;
  } else {
    bm = blockIdx.x / ntn;
    bn = blockIdx.x - bm * ntn;
  }
  const int m0 = bm << 7, n0 = bn << 7;

  const int lrow = tid >> 2;                 // 0..63
  const int cc   = tid & 3;                  // physical 16B chunk
  const int gcol = (cc ^ ((lrow >> 1) & 3)) << 3;

  f32x4 acc[4][4];
#pragma unroll
  for (int ii = 0; ii < 4; ++ii)
#pragma unroll
    for (int jj = 0; jj < 4; ++jj)
      acc[ii][jj] = f32x4{0.f, 0.f, 0.f, 0.f};

  const int mbase = (w & 1) << 6;
  const int nbase = (w >> 1) << 6;
  const int fr = lane & 15;
  const int fq = lane >> 4;
  const int rchunk = (fq ^ ((fr >> 1) & 3)) << 3;

  for (int kt = 0; kt < K; kt += 32) {
#pragma unroll
    for (int q = 0; q < 2; ++q) {
      const int mrow = (q << 6) + lrow;
      gload_lds16(A  + (size_t)(m0 + mrow) * K + (kt + gcol),
                  (char*)As + (q << 12) + (w << 10));
      gload_lds16(BT + (size_t)(n0 + mrow) * K + (kt + gcol),
                  (char*)Bs + (q << 12) + (w << 10));
    }
    __syncthreads();
    bf16x8 af[4], bfv[4];
#pragma unroll
    for (int ii = 0; ii < 4; ++ii) {
      af[ii]  = *(const bf16x8*)(As + ((mbase + (ii << 4) + fr) << 5) + rchunk);
      bfv[ii] = *(const bf16x8*)(Bs + ((nbase + (ii << 4) + fr) << 5) + rchunk);
    }
#pragma unroll
    for (int ii = 0; ii < 4; ++ii)
#pragma unroll
      for (int jj = 0; jj < 4; ++jj)
        acc[ii][jj] = __builtin_amdgcn_mfma_f32_16x16x32_bf16(af[ii], bfv[jj], acc[ii][jj], 0, 0, 0);
    __syncthreads();
  }

  if constexpr (MODE == 2) {
    // ---- fused layer-4 epilogue + layer-5 blend (N == 128) ----
    __shared__ u16 tile[128 * 136];
#pragma unroll
    for (int jj = 0; jj < 4; ++jj) {
      const int col = nbase + (jj << 4) + fr;
      const float bi = bias[col];
#pragma unroll
      for (int ii = 0; ii < 4; ++ii) {
#pragma unroll
        for (int r = 0; r < 4; ++r) {
          const int row = mbase + (ii << 4) + (fq << 2) + r;
          tile[row * 136 + col] = f2bf(fmaxf(acc[ii][jj][r] + bi, 0.f));
        }
      }
    }
    // preload w5 columns for this lane's 8 channels
    const int cbase = (lane & 15) << 3;
    float w50[8], w51[8];
#pragma unroll
    for (int j = 0; j < 8; ++j) {
      w50[j] = w5[((cbase + j) << 1) + 0];
      w51[j] = w5[((cbase + j) << 1) + 1];
    }
    const float b50 = b5[0], b51 = b5[1];
    __syncthreads();
#pragma unroll
    for (int rep = 0; rep < 8; ++rep) {
      const int pl = w + (rep << 2);              // block-local pixel 0..31
      const int row = (pl << 2) + fq;             // k = fq
      const u16x8 v = *(const u16x8*)(tile + row * 136 + cbase);
      float s0 = 0.f, s1 = 0.f;
#pragma unroll
      for (int j = 0; j < 8; ++j) {
        const float a = bf2f(v[j]);
        s0 += a * w50[j];
        s1 += a * w51[j];
      }
#pragma unroll
      for (int off = 8; off >= 1; off >>= 1) {
        s0 += __shfl_xor(s0, off, 16);
        s1 += __shfl_xor(s1, off, 16);
      }
      float p0[4], p1[4];
#pragma unroll
      for (int k = 0; k < 4; ++k) {
        p0[k] = __shfl(s0, k << 4, 64) + b50;
        p1[k] = __shfl(s1, k << 4, 64) + b51;
      }
      if (lane == 0) {
        float mx = fmaxf(fmaxf(p1[0], p1[1]), fmaxf(p1[2], p1[3]));
        float e0 = expf(p1[0] - mx), e1 = expf(p1[1] - mx);
        float e2 = expf(p1[2] - mx), e3 = expf(p1[3] - mx);
        outp[gp0 + (m0 >> 2) + pl] =
            (p0[0] * e0 + p0[1] * e1 + p0[2] * e2 + p0[3] * e3) / (e0 + e1 + e2 + e3);
      }
    }
  } else {
#pragma unroll
    for (int jj = 0; jj < 4; ++jj) {
      const int ncol = n0 + nbase + (jj << 4) + fr;
      const float bi = (MODE == 0) ? bias[ncol] : 0.f;
#pragma unroll
      for (int ii = 0; ii < 4; ++ii) {
#pragma unroll
        for (int r = 0; r < 4; ++r) {
          const int mrow = m0 + mbase + (ii << 4) + (fq << 2) + r;
          if (MODE == 0) {
            ((u16*)Cout)[(size_t)mrow * N + ncol] = f2bf(fmaxf(acc[ii][jj][r] + bi, 0.f));
          } else if (MODE == 1) {
            ((float*)Cout)[(size_t)mrow * N + ncol] = acc[ii][jj][r];
          } else {  // MODE 3
            ((u16*)Cout)[(size_t)mrow * N + ncol] = f2bf(acc[ii][jj][r]);
          }
        }
      }
    }
  }
}

// ---------------------------------------------------------------------------
// expand_a1: wave per pixel. A1[(p*4+k)][c] = relu(Yhr[p][c] + b1[c] +
//            Ycell[cell[k]][c] + ry*w1rel0[c] + rx*w1rel1[c])   — all coalesced.
// ---------------------------------------------------------------------------
__global__ __launch_bounds__(256)
void expand_a1(const u16* __restrict__ Yhr, const float* __restrict__ Ycell,
               const float* __restrict__ b1, const float* __restrict__ w1rel,
               const int* __restrict__ cellidx, const float* __restrict__ rel,
               u16* __restrict__ A1, int gp0)
{
  const int lane = threadIdx.x & 63;
  const int wv = threadIdx.x >> 6;
  const int p = (blockIdx.x << 2) + wv;        // chunk-local pixel
  const int gpix = gp0 + p;

  const int4   civ = *(const int4*)(cellidx + (size_t)gpix * 4);
  const float4 ra  = *(const float4*)(rel + (size_t)gpix * 8);
  const float4 rb  = *(const float4*)(rel + (size_t)gpix * 8 + 4);
  const int   cis[4] = {civ.x, civ.y, civ.z, civ.w};
  const float ry[4]  = {ra.x, ra.z, rb.x, rb.z};
  const float rx[4]  = {ra.y, ra.w, rb.y, rb.w};

#pragma unroll
  for (int s = 0; s < 4; ++s) {
    const int col = (s << 8) + (lane << 2);
    const u16x4 yh = *(const u16x4*)(Yhr + (size_t)p * 1024 + col);
    const float4 bv = *(const float4*)(b1 + col);
    const float4 w0 = *(const float4*)(w1rel + col);
    const float4 w1v = *(const float4*)(w1rel + 1024 + col);
    float base[4];
    base[0] = bf2f(yh[0]) + bv.x;
    base[1] = bf2f(yh[1]) + bv.y;
    base[2] = bf2f(yh[2]) + bv.z;
    base[3] = bf2f(yh[3]) + bv.w;
#pragma unroll
    for (int k = 0; k < 4; ++k) {
      float4 yc = {0.f, 0.f, 0.f, 0.f};
      if (cis[k] >= 0) yc = *(const float4*)(Ycell + (size_t)cis[k] * 1024 + col);
      u16x4 o;
      o[0] = f2bf(fmaxf(base[0] + yc.x + ry[k] * w0.x + rx[k] * w1v.x, 0.f));
      o[1] = f2bf(fmaxf(base[1] + yc.y + ry[k] * w0.y + rx[k] * w1v.y, 0.f));
      o[2] = f2bf(fmaxf(base[2] + yc.z + ry[k] * w0.z + rx[k] * w1v.z, 0.f));
      o[3] = f2bf(fmaxf(base[3] + yc.w + ry[k] * w0.w + rx[k] * w1v.w, 0.f));
      *(u16x4*)(A1 + (size_t)((p << 2) + k) * 1024 + col) = o;
    }
  }
}

// ---------------------------------------------------------------------------
// Weight prep
// ---------------------------------------------------------------------------
__global__ void prep_w1hr(const float* __restrict__ w1, u16* __restrict__ o) {
  const int idx = blockIdx.x * 256 + threadIdx.x;       // [1024][128]
  const int n = idx >> 7, k = idx & 127;
  o[idx] = f2bf(w1[(128 + k) * 1024 + n] + w1[(256 + k) * 1024 + n]);
}
__global__ void prep_w1cell(const float* __restrict__ w1, u16* __restrict__ o) {
  const int idx = blockIdx.x * 256 + threadIdx.x;       // [1024][256]
  const int n = idx >> 8, k = idx & 255;
  const float v = (k < 128) ? w1[k * 1024 + n] : w1[(128 + k) * 1024 + n];
  o[idx] = f2bf(v);
}
__global__ void prep_wt(const float* __restrict__ w, u16* __restrict__ wt, int K, int N) {
  const int idx = blockIdx.x * 256 + threadIdx.x;
  if (idx >= K * N) return;
  const int k = idx % K;
  const int n = idx / K;
  wt[idx] = f2bf(w[(size_t)k * N + n]);
}

// ---------------------------------------------------------------------------
extern "C" void kernel_launch(void* const* d_in, const int* in_sizes, int n_in,
                              void* d_out, int out_size, void* d_ws, size_t ws_size,
                              hipStream_t stream)
{
  const float* feat  = (const float*)d_in[0];
  const float* coord = (const float*)d_in[1];
  const float* hrg   = (const float*)d_in[2];
  const float* lrg   = (const float*)d_in[3];
  const float* w1 = (const float*)d_in[4];
  const float* b1 = (const float*)d_in[5];
  const float* w2 = (const float*)d_in[6];
  const float* b2 = (const float*)d_in[7];
  const float* w3 = (const float*)d_in[8];
  const float* b3 = (const float*)d_in[9];
  const float* w4 = (const float*)d_in[10];
  const float* b4 = (const float*)d_in[11];
  const float* w5 = (const float*)d_in[12];
  const float* b5 = (const float*)d_in[13];
  float* out = (float*)d_out;

  char* base = (char*)d_ws;
  u16* W1hrT   = (u16*)base;                       // [1024][128]
  u16* W1cellT = W1hrT + 1024 * 128;               // [1024][256]
  u16* W2T     = W1cellT + 1024 * 256;             // [512][1024]
  u16* W3T     = W2T + 512 * 1024;                 // [256][512]
  u16* W4T     = W3T + 256 * 512;                  // [128][256]
  u16* Xcell   = W4T + 128 * 256;                  // [8192][256]
  float* Ycell = (float*)(Xcell + 8192 * 256);     // [8192][1024] fp32
  u16* Xhr     = (u16*)(Ycell + (size_t)8192 * 1024);  // [131072][128]
  float* relb  = (float*)(Xhr + (size_t)131072 * 128); // [131072][4][2]
  int* cellidx = (int*)(relb + (size_t)131072 * 8);    // [131072][4]
  char* chunk_base = (char*)(cellidx + (size_t)131072 * 4);
  const size_t fixed = (size_t)(chunk_base - base);

  const int NP = 131072;
  // per-pixel chunk bytes: Yhr/A3 2048 + A1 8192 + A2 4096 = 14336 (A3 aliases Yhr)
  int nc = 1;
  while (nc < 128 && fixed + (size_t)(NP / nc) * 14336ULL > ws_size) nc <<= 1;
  const int CP = NP / nc;
  const int R = CP * 4;

  u16* Yhr = (u16*)chunk_base;          // [CP][1024] bf16 ; later A3 [R][256] bf16
  u16* A1  = Yhr + (size_t)CP * 1024;   // [R][1024] bf16
  u16* A2  = A1 + (size_t)R * 1024;     // [R][512] bf16
  u16* A3  = Yhr;                       // alias (Yhr dead after expand_a1)

  prep_w1hr<<<(1024 * 128) / 256, 256, 0, stream>>>(w1, W1hrT);
  prep_w1cell<<<(1024 * 256) / 256, 256, 0, stream>>>(w1, W1cellT);
  prep_wt<<<(1024 * 512) / 256, 256, 0, stream>>>(w2, W2T, 1024, 512);
  prep_wt<<<(512 * 256) / 256, 256, 0, stream>>>(w3, W3T, 512, 256);
  prep_wt<<<(256 * 128) / 256, 256, 0, stream>>>(w4, W4T, 256, 128);
  gather_hr<<<NP / 64, 256, 0, stream>>>(coord, hrg, Xhr, cellidx, relb);
  prep_cells<<<8192 / 64, 256, 0, stream>>>(feat, lrg, Xcell);
  // Ycell = Xcell @ W1cellT^T (fp32 raw)
  gemm_bt<1><<<(8192 / 128) * (1024 / 128), 256, 0, stream>>>(
      Xcell, W1cellT, (void*)Ycell, nullptr, 8192, 1024, 256,
      nullptr, nullptr, nullptr, 0);

  for (int ch = 0; ch < nc; ++ch) {
    const int gp0 = ch * CP;
    // Yhr = Xhr_chunk @ W1hrT^T (raw bf16)
    gemm_bt<3><<<(CP / 128) * (1024 / 128), 256, 0, stream>>>(
        Xhr + (size_t)gp0 * 128, W1hrT, (void*)Yhr, nullptr, CP, 1024, 128,
        nullptr, nullptr, nullptr, 0);
    expand_a1<<<CP / 4, 256, 0, stream>>>(
        Yhr, Ycell, b1, w1 + 384 * 1024, cellidx, relb, A1, gp0);
    gemm_bt<0><<<(R / 128) * (512 / 128), 256, 0, stream>>>(
        A1, W2T, (void*)A2, b2, R, 512, 1024, nullptr, nullptr, nullptr, 0);
    gemm_bt<0><<<(R / 128) * (256 / 128), 256, 0, stream>>>(
        A2, W3T, (void*)A3, b3, R, 256, 512, nullptr, nullptr, nullptr, 0);
    gemm_bt<2><<<(R / 128) * (128 / 128), 256, 0, stream>>>(
        A3, W4T, nullptr, b4, R, 128, 256, w5, b5, out, gp0);
  }
}